// Round 16
// baseline (670.650 us; speedup 1.0000x reference)
//
#include <hip/hip_runtime.h>
#include <hip/hip_bf16.h>

using bf16 = __hip_bfloat16;
typedef __attribute__((ext_vector_type(8))) short bf16x8;
typedef __attribute__((ext_vector_type(4))) float f32x4;

#define D_MODEL 1024
#define NHEAD 16
#define HEAD_DIM 64
#define D_FF 4096
#define SEQ 2048
#define NTOK 8192  // 4 * 2048

__device__ __forceinline__ void gload16(const void* g, void* l) {
  __builtin_amdgcn_global_load_lds((const __attribute__((address_space(1))) void*)g,
                                   (__attribute__((address_space(3))) void*)l, 16, 0, 0);
}

__device__ __forceinline__ unsigned pkbf16(float lo, float hi) {
  unsigned r;
  asm("v_cvt_pk_bf16_f32 %0, %1, %2" : "=v"(r) : "v"(lo), "v"(hi));
  return r;
}

// raw v_exp_f32 (2^x): exp2f() lowers to OCML multi-instr; this is 1 VALU op.
__device__ __forceinline__ float fexp2(float x) {
  float r;
  asm("v_exp_f32 %0, %1" : "=v"(r) : "v"(x));
  return r;
}

__device__ __forceinline__ float max3f(float a, float b, float c) {
  return fmaxf(fmaxf(a, b), c);  // fuses to v_max3_f32
}

// ---------------------------------------------------------------------------
// Fused: f32->bf16 weight conversion (blocks 0..12287) + LN1 (blocks 12288+).
// ---------------------------------------------------------------------------
__global__ __launch_bounds__(256) void cvt_ln(
    const float* __restrict__ W1, const float* __restrict__ W2,
    const float* __restrict__ Wq, const float* __restrict__ Wk,
    const float* __restrict__ Wv, const float* __restrict__ Wo,
    bf16* __restrict__ w1_b, bf16* __restrict__ w2_b,
    bf16* __restrict__ wqkv, bf16* __restrict__ wo_b,
    const float* __restrict__ x, const float* __restrict__ g,
    const float* __restrict__ bta, bf16* __restrict__ xn) {
  const int bid = blockIdx.x;
  if (bid < 12288) {
    const float* src;
    bf16* dst;
    int lb;
    if (bid < 4096) { src = W1; dst = w1_b; lb = bid; }
    else if (bid < 8192) { src = W2; dst = w2_b; lb = bid - 4096; }
    else {
      const int j = (bid - 8192) >> 10;
      lb = (bid - 8192) & 1023;
      if (j == 0) { src = Wq; dst = wqkv; }
      else if (j == 1) { src = Wk; dst = wqkv + 1048576; }
      else if (j == 2) { src = Wv; dst = wqkv + 2097152; }
      else { src = Wo; dst = wo_b; }
    }
    const int i = (lb * 256 + threadIdx.x) * 4;
    const float4 v = *(const float4*)&src[i];
    dst[i + 0] = __float2bfloat16(v.x);
    dst[i + 1] = __float2bfloat16(v.y);
    dst[i + 2] = __float2bfloat16(v.z);
    dst[i + 3] = __float2bfloat16(v.w);
    return;
  }
  const int row = bid - 12288, t = threadIdx.x;
  const float4 v = *(const float4*)&x[(size_t)row * D_MODEL + t * 4];
  float s = v.x + v.y + v.z + v.w;
#pragma unroll
  for (int m = 1; m < 64; m <<= 1) s += __shfl_xor(s, m);
  __shared__ float red[4], red2[4];
  const int w = t >> 6, l = t & 63;
  if (l == 0) red[w] = s;
  __syncthreads();
  const float mu = (red[0] + red[1] + red[2] + red[3]) * (1.f / 1024.f);
  const float d0 = v.x - mu, d1 = v.y - mu, d2 = v.z - mu, d3 = v.w - mu;
  float q = d0 * d0 + d1 * d1 + d2 * d2 + d3 * d3;
#pragma unroll
  for (int m = 1; m < 64; m <<= 1) q += __shfl_xor(q, m);
  if (l == 0) red2[w] = q;
  __syncthreads();
  const float var = (red2[0] + red2[1] + red2[2] + red2[3]) * (1.f / 1024.f);
  const float rs = rsqrtf(var + 1e-5f);
  const float4 gg = *(const float4*)&g[t * 4];
  const float4 bb = *(const float4*)&bta[t * 4];
  bf16* o = xn + (size_t)row * D_MODEL + t * 4;
  o[0] = __float2bfloat16(d0 * rs * gg.x + bb.x);
  o[1] = __float2bfloat16(d1 * rs * gg.y + bb.y);
  o[2] = __float2bfloat16(d2 * rs * gg.z + bb.z);
  o[3] = __float2bfloat16(d3 * rs * gg.w + bb.w);
}

// ---------------------------------------------------------------------------
// LayerNorm over D=1024, fp32 in -> bf16 out. One block (256 thr) per row.
// ---------------------------------------------------------------------------
__global__ __launch_bounds__(256) void layernorm_kernel(
    const float* __restrict__ xin, const float* __restrict__ g,
    const float* __restrict__ bta, bf16* __restrict__ out) {
  const int row = blockIdx.x, t = threadIdx.x;
  const float4 v = *(const float4*)&xin[(size_t)row * D_MODEL + t * 4];
  float s = v.x + v.y + v.z + v.w;
#pragma unroll
  for (int m = 1; m < 64; m <<= 1) s += __shfl_xor(s, m);
  __shared__ float red[4], red2[4];
  const int w = t >> 6, l = t & 63;
  if (l == 0) red[w] = s;
  __syncthreads();
  const float mu = (red[0] + red[1] + red[2] + red[3]) * (1.f / 1024.f);
  const float d0 = v.x - mu, d1 = v.y - mu, d2 = v.z - mu, d3 = v.w - mu;
  float q = d0 * d0 + d1 * d1 + d2 * d2 + d3 * d3;
#pragma unroll
  for (int m = 1; m < 64; m <<= 1) q += __shfl_xor(q, m);
  if (l == 0) red2[w] = q;
  __syncthreads();
  const float var = (red2[0] + red2[1] + red2[2] + red2[3]) * (1.f / 1024.f);
  const float rs = rsqrtf(var + 1e-5f);
  const float4 gg = *(const float4*)&g[t * 4];
  const float4 bb = *(const float4*)&bta[t * 4];
  bf16* o = out + (size_t)row * D_MODEL + t * 4;
  o[0] = __float2bfloat16(d0 * rs * gg.x + bb.x);
  o[1] = __float2bfloat16(d1 * rs * gg.y + bb.y);
  o[2] = __float2bfloat16(d2 * rs * gg.z + bb.z);
  o[3] = __float2bfloat16(d3 * rs * gg.w + bb.w);
}

// ---------------------------------------------------------------------------
// gemmA: BM=256,BN=256,BK=64, 512 thr, 8 waves (2M x 4N). (frozen)
// ---------------------------------------------------------------------------
template <int MODE>
__global__ __launch_bounds__(512, 2) void gemmA(
    const bf16* __restrict__ A, const bf16* __restrict__ Bw,
    const float* __restrict__ bias0,
    void* __restrict__ out, int M, int N, int K) {
  constexpr int ASZ = 256 * 128;
  constexpr int TILE = ASZ + 256 * 128;  // 64 KB
  __shared__ __align__(16) char smem[2 * TILE];

  const int t = threadIdx.x;
  const int l = t & 63, l15 = l & 15, l4 = (l >> 4) & 3;
  const int w = t >> 6, wm = w >> 2, wn = w & 3;
  const int gx = gridDim.x;
  const int nwg = gx * gridDim.y;
  const int bid0 = blockIdx.y * gx + blockIdx.x;
  const int bid = (bid0 & 7) * (nwg >> 3) + (bid0 >> 3);
  const int m0 = (bid / gx) * 256, n0 = (bid % gx) * 256;

  const int sr = t >> 3;
  const int scol = 8 * ((t & 7) ^ (sr & 7));
  const int swz = (l15 & 7) << 4;
  int coff[2];
  coff[0] = (l4 * 16) ^ swz;
  coff[1] = (64 + l4 * 16) ^ swz;

#define ST_A(j, kb, buf)                                          \
  gload16(&A[(size_t)(m0 + (j) * 64 + sr) * K + (kb) + scol],     \
          (void*)(smem + (buf) * TILE + (j) * 8192 + t * 16))
#define ST_B(j, kb, buf)                                          \
  gload16(&Bw[(size_t)(n0 + (j) * 64 + sr) * K + (kb) + scol],    \
          (void*)(smem + (buf) * TILE + ASZ + (j) * 8192 + t * 16))

  f32x4 acc[8][4] = {};
  const int NTm = K >> 6;

  ST_A(0, 0, 0); ST_A(2, 0, 0); ST_B(0, 0, 0); ST_B(1, 0, 0);
  ST_B(2, 0, 0); ST_B(3, 0, 0); ST_A(1, 0, 0); ST_A(3, 0, 0);
  asm volatile("s_waitcnt vmcnt(0)" ::: "memory");
  __builtin_amdgcn_s_barrier();

  for (int kt = 0; kt < NTm; ++kt) {
    const char* cb = smem + (kt & 1) * TILE;
    const int nb = (kt & 1) ^ 1;
    const int kbn = (kt + 1) << 6;
    const bool hasNext = (kt + 1 < NTm);
#pragma unroll
    for (int kk = 0; kk < 2; ++kk) {
      if (hasNext) {
        if (kk == 0) { ST_A(0, kbn, nb); ST_A(2, kbn, nb); ST_B(0, kbn, nb); ST_B(1, kbn, nb); }
        else         { ST_B(2, kbn, nb); ST_B(3, kbn, nb); ST_A(1, kbn, nb); ST_A(3, kbn, nb); }
      }
      bf16x8 af[8], bfr[4];
#pragma unroll
      for (int mf = 0; mf < 8; ++mf)
        af[mf] = *(const bf16x8*)(cb + (wm * 128 + mf * 16 + l15) * 128 + coff[kk]);
#pragma unroll
      for (int nf = 0; nf < 4; ++nf)
        bfr[nf] = *(const bf16x8*)(cb + ASZ + (wn * 64 + nf * 16 + l15) * 128 + coff[kk]);
      __builtin_amdgcn_s_setprio(1);
#pragma unroll
      for (int mf = 0; mf < 8; ++mf)
#pragma unroll
        for (int nf = 0; nf < 4; ++nf)
          acc[mf][nf] = __builtin_amdgcn_mfma_f32_16x16x32_bf16(
              af[mf], bfr[nf], acc[mf][nf], 0, 0, 0);
      __builtin_amdgcn_s_setprio(0);
    }
    asm volatile("s_waitcnt vmcnt(0)" ::: "memory");
    __builtin_amdgcn_s_barrier();
  }
#undef ST_A
#undef ST_B

#pragma unroll
  for (int mf = 0; mf < 8; ++mf) {
#pragma unroll
    for (int nf = 0; nf < 4; ++nf) {
      const int col = n0 + wn * 64 + nf * 16 + l15;
      const float bb = bias0[col];
#pragma unroll
      for (int r = 0; r < 4; ++r) {
        const int row = m0 + wm * 128 + mf * 16 + l4 * 4 + r;
        float y = acc[mf][nf][r] + bb;
        if constexpr (MODE == 1) y = fmaxf(y, 0.f);
        ((bf16*)out)[(size_t)row * N + col] = __float2bfloat16(y);
      }
    }
  }
}

// ---------------------------------------------------------------------------
// gemmB: BM=128,BN=256,BK=64, 512 thr, 8 waves (2M x 4N). (frozen)
// MODE 0: QKV permute+split; MODE 2: f32 out += res
// ---------------------------------------------------------------------------
template <int MODE>
__global__ __launch_bounds__(512, 2) void gemmB(
    const bf16* __restrict__ A, const bf16* __restrict__ Bw,
    const float* __restrict__ bias0, const float* __restrict__ bias1,
    const float* __restrict__ bias2, const float* __restrict__ res,
    void* __restrict__ out, int M, int N, int K) {
  constexpr int ASZ = 128 * 128;
  constexpr int TILE = ASZ + 256 * 128;  // 48 KB
  __shared__ __align__(16) char smem[3 * TILE];  // 144 KB

  const int t = threadIdx.x;
  const int l = t & 63, l15 = l & 15, l4 = (l >> 4) & 3;
  const int w = t >> 6, wm = w >> 2, wn = w & 3;
  const int gx = gridDim.x;
  const int nwg = gx * gridDim.y;
  const int bid0 = blockIdx.y * gx + blockIdx.x;
  const int bid = (bid0 & 7) * (nwg >> 3) + (bid0 >> 3);
  const int m0 = (bid / gx) * 128, n0 = (bid % gx) * 256;

  const int sr = t >> 3;
  const int scol = 8 * ((t & 7) ^ (sr & 7));
  const int swz = (l15 & 7) << 4;
  int coff[2];
  coff[0] = (l4 * 16) ^ swz;
  coff[1] = (64 + l4 * 16) ^ swz;

#define ST_A(j, kb, buf)                                          \
  gload16(&A[(size_t)(m0 + (j) * 64 + sr) * K + (kb) + scol],     \
          (void*)(smem + (buf) * TILE + (j) * 8192 + t * 16))
#define ST_B(j, kb, buf)                                          \
  gload16(&Bw[(size_t)(n0 + (j) * 64 + sr) * K + (kb) + scol],    \
          (void*)(smem + (buf) * TILE + ASZ + (j) * 8192 + t * 16))

  f32x4 acc[4][4] = {};
  const int NTm = K >> 6;

  ST_B(0, 0, 0); ST_B(1, 0, 0); ST_B(2, 0, 0);
  ST_B(3, 0, 0); ST_A(0, 0, 0); ST_A(1, 0, 0);
  ST_B(0, 64, 1); ST_B(1, 64, 1); ST_B(2, 64, 1);
  ST_B(3, 64, 1); ST_A(0, 64, 1); ST_A(1, 64, 1);
  asm volatile("s_waitcnt vmcnt(6)" ::: "memory");
  __builtin_amdgcn_s_barrier();

  for (int kt = 0; kt < NTm; ++kt) {
    const char* cb = smem + (kt % 3) * TILE;
    const int nb = (kt + 2) % 3;
    const int kbn = (kt + 2) << 6;
    const bool iss = (kt + 2 < NTm);
    if (iss) {
      ST_B(0, kbn, nb); ST_B(1, kbn, nb); ST_B(2, kbn, nb);
      ST_B(3, kbn, nb); ST_A(0, kbn, nb); ST_A(1, kbn, nb);
    }
    bf16x8 af[2][4], bfr[2][4];
#pragma unroll
    for (int kk = 0; kk < 2; ++kk) {
#pragma unroll
      for (int mf = 0; mf < 4; ++mf)
        af[kk][mf] = *(const bf16x8*)(cb + (wm * 64 + mf * 16 + l15) * 128 + coff[kk]);
#pragma unroll
      for (int nf = 0; nf < 4; ++nf)
        bfr[kk][nf] = *(const bf16x8*)(cb + ASZ + (wn * 64 + nf * 16 + l15) * 128 + coff[kk]);
    }
    __builtin_amdgcn_s_setprio(1);
#pragma unroll
    for (int kk = 0; kk < 2; ++kk)
#pragma unroll
      for (int mf = 0; mf < 4; ++mf)
#pragma unroll
        for (int nf = 0; nf < 4; ++nf)
          acc[mf][nf] = __builtin_amdgcn_mfma_f32_16x16x32_bf16(
              af[kk][mf], bfr[kk][nf], acc[mf][nf], 0, 0, 0);
    __builtin_amdgcn_s_setprio(0);
    if (iss) asm volatile("s_waitcnt vmcnt(6)" ::: "memory");
    else     asm volatile("s_waitcnt vmcnt(0)" ::: "memory");
    __builtin_amdgcn_s_barrier();
  }
#undef ST_A
#undef ST_B

#pragma unroll
  for (int mf = 0; mf < 4; ++mf) {
#pragma unroll
    for (int nf = 0; nf < 4; ++nf) {
      const int col = n0 + wn * 64 + nf * 16 + l15;
      float bb;
      if constexpr (MODE == 0) {
        const int sel = col >> 10;
        const float* bp = (sel == 0) ? bias0 : ((sel == 1) ? bias1 : bias2);
        bb = bp[col & 1023];
      } else {
        bb = bias0[col];
      }
#pragma unroll
      for (int r = 0; r < 4; ++r) {
        const int row = m0 + wm * 64 + mf * 16 + l4 * 4 + r;
        float y = acc[mf][nf][r] + bb;
        if constexpr (MODE == 0) {
          const int sel = col >> 10;
          const int c10 = col & 1023;
          const size_t dst = (size_t)sel * (NTOK * 1024) +
                             (size_t)((row >> 11) * NHEAD + (c10 >> 6)) * (SEQ * HEAD_DIM) +
                             (size_t)(row & (SEQ - 1)) * HEAD_DIM + (c10 & 63);
          ((bf16*)out)[dst] = __float2bfloat16(y);
        } else {
          y += res[(size_t)row * N + col];
          ((float*)out)[(size_t)row * N + col] = y;
        }
      }
    }
  }
}

// ---------------------------------------------------------------------------
// Flash attention v12: lean v11 body at 256 threads / QBLK=128 / grid 1024,
// __launch_bounds__(256,5) -> 5 blocks/CU (LDS 5x32KB = 160KB exact), i.e.
// 5 waves/SIMD vs r15's 4. TLP is the only lever that has moved flash twice
// (r8 −14%, r14 −9%); both pipes still <60% busy at 4 waves/SIMD.
// ---------------------------------------------------------------------------
#define SCL 0.18033688011112042f  // 0.125 * log2(e)
#define NT (SEQ / 64)

__global__ __launch_bounds__(256, 5) void flash_attn(
    const bf16* __restrict__ Q, const bf16* __restrict__ K,
    const bf16* __restrict__ V, bf16* __restrict__ O) {
  __shared__ char smem[32768];  // K dbuf @0..16K, Vt dbuf @16K..32K
  const int t = threadIdx.x;
  const int w = t >> 6, l = t & 63;
  const int l15 = l & 15, l4 = l >> 4;
  // XCD swizzle over 1024 blocks
  const int bid0 = blockIdx.y * 16 + blockIdx.x;
  const int bid = (bid0 & 7) * 128 + (bid0 >> 3);
  const int bx = bid & 15, bh = bid >> 4;
  const size_t base = (size_t)bh * (SEQ * HEAD_DIM);
  const int q0 = bx * 128 + w * 32;

  int krow[4], kswz[4];
#pragma unroll
  for (int ni = 0; ni < 4; ++ni) {
    const int kr = (ni >> 1) * 32 + (ni & 1) * 4 + (l15 >> 2) * 8 + (l15 & 3);
    krow[ni] = kr * 128;
    kswz[ni] = ((kr & 3) | (((kr >> 3) & 1) << 2)) << 4;
  }

  bf16x8 qf[2][2];
#pragma unroll
  for (int mi = 0; mi < 2; ++mi)
#pragma unroll
    for (int kk = 0; kk < 2; ++kk)
      qf[mi][kk] = *(const bf16x8*)&Q[base + (size_t)(q0 + mi * 16 + l15) * 64 + kk * 32 + l4 * 8];

  f32x4 accO[2][4] = {};
  float m_run[2], l_run[2];
#pragma unroll
  for (int mi = 0; mi < 2; ++mi) { m_run[mi] = -1e30f; l_run[mi] = 0.f; }

  short vg[16];

  // staging geometry (256 threads, r7 form):
  // K: thread covers rows t>>3 and (t>>3)+32, 16B chunk (t&7), inverse-swz src
  const int r0 = t >> 3;
  const int c0 = 8 * ((t & 7) ^ ((r0 & 3) | (((r0 >> 3) & 1) << 2)));
  const int r1 = r0 + 32;
  const int c1 = 8 * ((t & 7) ^ ((r1 & 3) | (((r1 >> 3) & 1) << 2)));
  const short* kg0 = (const short*)K + base + r0 * 64 + c0;
  const short* kg1 = (const short*)K + base + r1 * 64 + c1;
  // V: d-column dV = w*16+l15, k = l4*8..+8 (vp0) and +32 (vp1)
  const int dV = w * 16 + l15;
  const short* vp0 = (const short*)V + base + (size_t)(l4 * 8) * 64 + dV;
  const short* vp1 = vp0 + 2048;

#define STAGE_K(bufofs)                                          \
  {                                                              \
    gload16(kg0, (void*)(smem + (bufofs) + w * 1024));           \
    gload16(kg1, (void*)(smem + (bufofs) + 4096 + w * 1024));    \
    kg0 += 4096; kg1 += 4096;                                    \
  }

#define V_GATHER()                                               \
  {                                                              \
    _Pragma("unroll") for (int j_ = 0; j_ < 8; ++j_) {           \
      vg[j_] = vp0[j_ * 64];                                     \
      vg[8 + j_] = vp1[j_ * 64];                                 \
    }                                                            \
    vp0 += 4096; vp1 += 4096;                                    \
  }

#define VT_WRITE(bufofs)                                                          \
  {                                                                               \
    _Pragma("unroll") for (int h_ = 0; h_ < 2; ++h_) {                            \
      bf16x8 vv;                                                                  \
      _Pragma("unroll") for (int j_ = 0; j_ < 8; ++j_) vv[j_] = vg[h_ * 8 + j_];  \
      const int kb_ = (h_ * 64 + l4 * 16) ^ ((dV & 7) << 4);                      \
      *(bf16x8*)(smem + (bufofs) + dV * 128 + kb_) = vv;                          \
    }                                                                             \
  }

  STAGE_K(0);
  V_GATHER();
  VT_WRITE(16384);
  __syncthreads();

  for (int it = 0; it < NT; ++it) {
    const int cur = it & 1;
    const char* Kb = (const char*)smem + cur * 8192;
    const char* Vb = (const char*)smem + 16384 + cur * 8192;
    const bool pre = (it + 1 < NT);
    if (pre) {
      STAGE_K((cur ^ 1) * 8192);
      V_GATHER();
    }

    // ---- QK^T (swapped), kk-outer so kf lives briefly ----
    f32x4 s[2][4] = {};
#pragma unroll
    for (int kk = 0; kk < 2; ++kk) {
      bf16x8 kf[4];
#pragma unroll
      for (int ni = 0; ni < 4; ++ni)
        kf[ni] = *(const bf16x8*)(Kb + krow[ni] + ((kk * 64 + l4 * 16) ^ kswz[ni]));
      __builtin_amdgcn_s_setprio(1);
#pragma unroll
      for (int mi = 0; mi < 2; ++mi)
#pragma unroll
        for (int ni = 0; ni < 4; ++ni)
          s[mi][ni] = __builtin_amdgcn_mfma_f32_16x16x32_bf16(kf[ni], qf[mi][kk], s[mi][ni], 0, 0, 0);
      __builtin_amdgcn_s_setprio(0);
    }

    // ---- softmax per mi (in place on s) ----
#pragma unroll
    for (int mi = 0; mi < 2; ++mi) {
      const float t0 = max3f(s[mi][0][0], s[mi][0][1], s[mi][0][2]);
      const float t1 = max3f(s[mi][0][3], s[mi][1][0], s[mi][1][1]);
      const float t2 = max3f(s[mi][1][2], s[mi][1][3], s[mi][2][0]);
      const float t3 = max3f(s[mi][2][1], s[mi][2][2], s[mi][2][3]);
      const float t4 = max3f(s[mi][3][0], s[mi][3][1], s[mi][3][2]);
      float mx = fmaxf(max3f(t1, t2, t3), fmaxf(t4, fmaxf(t0, s[mi][3][3])));
      mx = fmaxf(mx, __shfl_xor(mx, 16));
      mx = fmaxf(mx, __shfl_xor(mx, 32));
      const float mxs = mx * SCL;
      // defer-rescale (T13)
      if (__any(mxs > m_run[mi] + 8.f)) {
        const float mn = fmaxf(m_run[mi], mxs);
        const float c = fexp2(m_run[mi] - mn);
        m_run[mi] = mn;
        l_run[mi] *= c;
#pragma unroll
        for (int ni = 0; ni < 4; ++ni)
#pragma unroll
          for (int r = 0; r < 4; ++r) accO[mi][ni][r] *= c;
      }
      float rs = 0.f;
#pragma unroll
      for (int ni = 0; ni < 4; ++ni)
#pragma unroll
        for (int r = 0; r < 4; ++r) {
          const float p = fexp2(fmaf(s[mi][ni][r], SCL, -m_run[mi]));
          s[mi][ni][r] = p;
          rs += p;
        }
      rs += __shfl_xor(rs, 16);
      rs += __shfl_xor(rs, 32);
      l_run[mi] += rs;
    }

    // ---- PV: kk-outer, pb packed inline from live s ----
#pragma unroll
    for (int kk = 0; kk < 2; ++kk) {
      bf16x8 vf[4];
#pragma unroll
      for (int ni = 0; ni < 4; ++ni)
        vf[ni] = *(const bf16x8*)(Vb + (ni * 16 + l15) * 128 +
                                  ((kk * 64 + l4 * 16) ^ ((l15 & 7) << 4)));
#pragma unroll
      for (int mi = 0; mi < 2; ++mi) {
        union { unsigned u[4]; bf16x8 h; } pb;
#pragma unroll
        for (int jj = 0; jj < 4; ++jj) {
          const int ni = 2 * kk + (jj >> 1);
          pb.u[jj] = pkbf16(s[mi][ni][2 * (jj & 1)], s[mi][ni][2 * (jj & 1) + 1]);
        }
        __builtin_amdgcn_s_setprio(1);
#pragma unroll
        for (int ni = 0; ni < 4; ++ni)
          accO[mi][ni] = __builtin_amdgcn_mfma_f32_16x16x32_bf16(vf[ni], pb.h, accO[mi][ni], 0, 0, 0);
        __builtin_amdgcn_s_setprio(0);
      }
    }

    if (pre) VT_WRITE(16384 + (cur ^ 1) * 8192);
    __syncthreads();
  }

  // ---- epilogue: bounce O^T through LDS (4 KB/wave) for coalesced stores ----
  char* ob = smem + w * 4096;
#pragma unroll
  for (int mi = 0; mi < 2; ++mi) {
    const float inv = 1.f / l_run[mi];
    const int qr = mi * 16 + l15;
    const int sw = (qr & 7) << 4;
#pragma unroll
    for (int ni = 0; ni < 4; ++ni)
#pragma unroll
      for (int rr = 0; rr < 2; ++rr) {
        const unsigned pk = pkbf16(accO[mi][ni][2 * rr] * inv, accO[mi][ni][2 * rr + 1] * inv);
        *(unsigned*)(ob + qr * 128 + ((ni * 32 + l4 * 8 + 4 * rr) ^ sw)) = pk;
      }
  }
  asm volatile("s_waitcnt lgkmcnt(0)" ::: "memory");
  __builtin_amdgcn_sched_barrier(0);

  const int b = bh >> 4, h = bh & 15;
  const int hr = l >> 1, hf = l & 1;
  const size_t orow = ((size_t)b * SEQ + bx * 128 + w * 32 + hr) * D_MODEL + h * HEAD_DIM + hf * 32;
#pragma unroll
  for (int c = 0; c < 4; ++c) {
    bf16x8 vv = *(const bf16x8*)(ob + hr * 128 + (((hf * 64) + c * 16) ^ ((hr & 7) << 4)));
    *(bf16x8*)&O[orow + c * 8] = vv;
  }
}

// ---------------------------------------------------------------------------
extern "C" void kernel_launch(void* const* d_in, const int* in_sizes, int n_in,
                              void* d_out, int out_size, void* d_ws, size_t ws_size,
                              hipStream_t stream) {
  const float* x     = (const float*)d_in[0];
  const float* Wq    = (const float*)d_in[1];
  const float* bq    = (const float*)d_in[2];
  const float* Wk    = (const float*)d_in[3];
  const float* bk    = (const float*)d_in[4];
  const float* Wv    = (const float*)d_in[5];
  const float* bv    = (const float*)d_in[6];
  const float* Wo    = (const float*)d_in[7];
  const float* bo    = (const float*)d_in[8];
  const float* W1    = (const float*)d_in[9];
  const float* b1    = (const float*)d_in[10];
  const float* W2    = (const float*)d_in[11];
  const float* b2    = (const float*)d_in[12];
  const float* ln1_g = (const float*)d_in[13];
  const float* ln1_b = (const float*)d_in[14];
  const float* ln2_g = (const float*)d_in[15];
  const float* ln2_b = (const float*)d_in[16];

  const size_t MB = 1ull << 20;
  char* ws = (char*)d_ws;
  bf16* wqkv = (bf16*)(ws + 0 * MB);    // 6 MB: [Wq;Wk;Wv] rows, K-contig
  bf16* wo_b = (bf16*)(ws + 6 * MB);
  bf16* w1_b = (bf16*)(ws + 8 * MB);    // 8 MB
  bf16* w2_b = (bf16*)(ws + 16 * MB);   // 8 MB
  bf16* xn   = (bf16*)(ws + 24 * MB);   // 16 MB: xn / attn_out / xn2
  bf16* qb   = (bf16*)(ws + 40 * MB);   // 16 MB (q,k,v contiguous)
  bf16* kbuf = (bf16*)(ws + 56 * MB);   // 16 MB
  bf16* vb   = (bf16*)(ws + 72 * MB);   // 16 MB
  bf16* hb   = (bf16*)(ws + 40 * MB);   // 64 MB (reuses q/k/v after attention)
  float* x1  = (float*)(ws + 104 * MB); // 32 MB

  // weight conversion + LN1 fused into one launch
  cvt_ln<<<12288 + NTOK, 256, 0, stream>>>(W1, W2, Wq, Wk, Wv, Wo,
                                           w1_b, w2_b, wqkv, wo_b,
                                           x, ln1_g, ln1_b, xn);

  // QKV fused: [8192,3072] = xn @ wqkv^T -> permuted/split q/k/v
  gemmB<0><<<dim3(3072 / 256, NTOK / 128), 512, 0, stream>>>(
      xn, wqkv, bq, bk, bv, nullptr, qb, NTOK, 3072, 1024);

  flash_attn<<<dim3(SEQ / 128, 4 * NHEAD), 256, 0, stream>>>(qb, kbuf, vb, xn);

  // Wo + residual(x) -> x1 (fp32)
  gemmB<2><<<dim3(1024 / 256, NTOK / 128), 512, 0, stream>>>(
      xn, wo_b, bo, bo, bo, x, x1, NTOK, 1024, 1024);

  layernorm_kernel<<<NTOK, 256, 0, stream>>>(x1, ln2_g, ln2_b, xn);

  // FFN1 (ReLU) -> hb
  gemmA<1><<<dim3(D_FF / 256, NTOK / 256), 512, 0, stream>>>(
      xn, w1_b, b1, hb, NTOK, D_FF, 1024);

  // FFN2 + residual(x1) -> d_out (fp32)
  gemmB<2><<<dim3(1024 / 256, NTOK / 128), 512, 0, stream>>>(
      hb, w2_b, b2, b2, b2, x1, d_out, NTOK, 1024, D_FF);
}

// Round 17
// 370.761 us; speedup vs baseline: 1.8088x; 1.8088x over previous
//
#include <hip/hip_runtime.h>
#include <hip/hip_bf16.h>

using bf16 = __hip_bfloat16;
typedef __attribute__((ext_vector_type(8))) short bf16x8;
typedef __attribute__((ext_vector_type(4))) float f32x4;

#define D_MODEL 1024
#define NHEAD 16
#define HEAD_DIM 64
#define D_FF 4096
#define SEQ 2048
#define NTOK 8192  // 4 * 2048

__device__ __forceinline__ void gload16(const void* g, void* l) {
  __builtin_amdgcn_global_load_lds((const __attribute__((address_space(1))) void*)g,
                                   (__attribute__((address_space(3))) void*)l, 16, 0, 0);
}

__device__ __forceinline__ unsigned pkbf16(float lo, float hi) {
  unsigned r;
  asm("v_cvt_pk_bf16_f32 %0, %1, %2" : "=v"(r) : "v"(lo), "v"(hi));
  return r;
}

// raw v_exp_f32 (2^x): exp2f() lowers to OCML multi-instr; this is 1 VALU op.
__device__ __forceinline__ float fexp2(float x) {
  float r;
  asm("v_exp_f32 %0, %1" : "=v"(r) : "v"(x));
  return r;
}

__device__ __forceinline__ float max3f(float a, float b, float c) {
  return fmaxf(fmaxf(a, b), c);  // fuses to v_max3_f32
}

// ---------------------------------------------------------------------------
// Fused: f32->bf16 weight conversion (blocks 0..12287) + LN1 (blocks 12288+).
// ---------------------------------------------------------------------------
__global__ __launch_bounds__(256) void cvt_ln(
    const float* __restrict__ W1, const float* __restrict__ W2,
    const float* __restrict__ Wq, const float* __restrict__ Wk,
    const float* __restrict__ Wv, const float* __restrict__ Wo,
    bf16* __restrict__ w1_b, bf16* __restrict__ w2_b,
    bf16* __restrict__ wqkv, bf16* __restrict__ wo_b,
    const float* __restrict__ x, const float* __restrict__ g,
    const float* __restrict__ bta, bf16* __restrict__ xn) {
  const int bid = blockIdx.x;
  if (bid < 12288) {
    const float* src;
    bf16* dst;
    int lb;
    if (bid < 4096) { src = W1; dst = w1_b; lb = bid; }
    else if (bid < 8192) { src = W2; dst = w2_b; lb = bid - 4096; }
    else {
      const int j = (bid - 8192) >> 10;
      lb = (bid - 8192) & 1023;
      if (j == 0) { src = Wq; dst = wqkv; }
      else if (j == 1) { src = Wk; dst = wqkv + 1048576; }
      else if (j == 2) { src = Wv; dst = wqkv + 2097152; }
      else { src = Wo; dst = wo_b; }
    }
    const int i = (lb * 256 + threadIdx.x) * 4;
    const float4 v = *(const float4*)&src[i];
    dst[i + 0] = __float2bfloat16(v.x);
    dst[i + 1] = __float2bfloat16(v.y);
    dst[i + 2] = __float2bfloat16(v.z);
    dst[i + 3] = __float2bfloat16(v.w);
    return;
  }
  const int row = bid - 12288, t = threadIdx.x;
  const float4 v = *(const float4*)&x[(size_t)row * D_MODEL + t * 4];
  float s = v.x + v.y + v.z + v.w;
#pragma unroll
  for (int m = 1; m < 64; m <<= 1) s += __shfl_xor(s, m);
  __shared__ float red[4], red2[4];
  const int w = t >> 6, l = t & 63;
  if (l == 0) red[w] = s;
  __syncthreads();
  const float mu = (red[0] + red[1] + red[2] + red[3]) * (1.f / 1024.f);
  const float d0 = v.x - mu, d1 = v.y - mu, d2 = v.z - mu, d3 = v.w - mu;
  float q = d0 * d0 + d1 * d1 + d2 * d2 + d3 * d3;
#pragma unroll
  for (int m = 1; m < 64; m <<= 1) q += __shfl_xor(q, m);
  if (l == 0) red2[w] = q;
  __syncthreads();
  const float var = (red2[0] + red2[1] + red2[2] + red2[3]) * (1.f / 1024.f);
  const float rs = rsqrtf(var + 1e-5f);
  const float4 gg = *(const float4*)&g[t * 4];
  const float4 bb = *(const float4*)&bta[t * 4];
  bf16* o = xn + (size_t)row * D_MODEL + t * 4;
  o[0] = __float2bfloat16(d0 * rs * gg.x + bb.x);
  o[1] = __float2bfloat16(d1 * rs * gg.y + bb.y);
  o[2] = __float2bfloat16(d2 * rs * gg.z + bb.z);
  o[3] = __float2bfloat16(d3 * rs * gg.w + bb.w);
}

// ---------------------------------------------------------------------------
// LayerNorm over D=1024, fp32 in -> bf16 out. One block (256 thr) per row.
// ---------------------------------------------------------------------------
__global__ __launch_bounds__(256) void layernorm_kernel(
    const float* __restrict__ xin, const float* __restrict__ g,
    const float* __restrict__ bta, bf16* __restrict__ out) {
  const int row = blockIdx.x, t = threadIdx.x;
  const float4 v = *(const float4*)&xin[(size_t)row * D_MODEL + t * 4];
  float s = v.x + v.y + v.z + v.w;
#pragma unroll
  for (int m = 1; m < 64; m <<= 1) s += __shfl_xor(s, m);
  __shared__ float red[4], red2[4];
  const int w = t >> 6, l = t & 63;
  if (l == 0) red[w] = s;
  __syncthreads();
  const float mu = (red[0] + red[1] + red[2] + red[3]) * (1.f / 1024.f);
  const float d0 = v.x - mu, d1 = v.y - mu, d2 = v.z - mu, d3 = v.w - mu;
  float q = d0 * d0 + d1 * d1 + d2 * d2 + d3 * d3;
#pragma unroll
  for (int m = 1; m < 64; m <<= 1) q += __shfl_xor(q, m);
  if (l == 0) red2[w] = q;
  __syncthreads();
  const float var = (red2[0] + red2[1] + red2[2] + red2[3]) * (1.f / 1024.f);
  const float rs = rsqrtf(var + 1e-5f);
  const float4 gg = *(const float4*)&g[t * 4];
  const float4 bb = *(const float4*)&bta[t * 4];
  bf16* o = out + (size_t)row * D_MODEL + t * 4;
  o[0] = __float2bfloat16(d0 * rs * gg.x + bb.x);
  o[1] = __float2bfloat16(d1 * rs * gg.y + bb.y);
  o[2] = __float2bfloat16(d2 * rs * gg.z + bb.z);
  o[3] = __float2bfloat16(d3 * rs * gg.w + bb.w);
}

// ---------------------------------------------------------------------------
// gemmA: BM=256,BN=256,BK=64, 512 thr, 8 waves (2M x 4N). (frozen)
// ---------------------------------------------------------------------------
template <int MODE>
__global__ __launch_bounds__(512, 2) void gemmA(
    const bf16* __restrict__ A, const bf16* __restrict__ Bw,
    const float* __restrict__ bias0,
    void* __restrict__ out, int M, int N, int K) {
  constexpr int ASZ = 256 * 128;
  constexpr int TILE = ASZ + 256 * 128;  // 64 KB
  __shared__ __align__(16) char smem[2 * TILE];

  const int t = threadIdx.x;
  const int l = t & 63, l15 = l & 15, l4 = (l >> 4) & 3;
  const int w = t >> 6, wm = w >> 2, wn = w & 3;
  const int gx = gridDim.x;
  const int nwg = gx * gridDim.y;
  const int bid0 = blockIdx.y * gx + blockIdx.x;
  const int bid = (bid0 & 7) * (nwg >> 3) + (bid0 >> 3);
  const int m0 = (bid / gx) * 256, n0 = (bid % gx) * 256;

  const int sr = t >> 3;
  const int scol = 8 * ((t & 7) ^ (sr & 7));
  const int swz = (l15 & 7) << 4;
  int coff[2];
  coff[0] = (l4 * 16) ^ swz;
  coff[1] = (64 + l4 * 16) ^ swz;

#define ST_A(j, kb, buf)                                          \
  gload16(&A[(size_t)(m0 + (j) * 64 + sr) * K + (kb) + scol],     \
          (void*)(smem + (buf) * TILE + (j) * 8192 + t * 16))
#define ST_B(j, kb, buf)                                          \
  gload16(&Bw[(size_t)(n0 + (j) * 64 + sr) * K + (kb) + scol],    \
          (void*)(smem + (buf) * TILE + ASZ + (j) * 8192 + t * 16))

  f32x4 acc[8][4] = {};
  const int NTm = K >> 6;

  ST_A(0, 0, 0); ST_A(2, 0, 0); ST_B(0, 0, 0); ST_B(1, 0, 0);
  ST_B(2, 0, 0); ST_B(3, 0, 0); ST_A(1, 0, 0); ST_A(3, 0, 0);
  asm volatile("s_waitcnt vmcnt(0)" ::: "memory");
  __builtin_amdgcn_s_barrier();

  for (int kt = 0; kt < NTm; ++kt) {
    const char* cb = smem + (kt & 1) * TILE;
    const int nb = (kt & 1) ^ 1;
    const int kbn = (kt + 1) << 6;
    const bool hasNext = (kt + 1 < NTm);
#pragma unroll
    for (int kk = 0; kk < 2; ++kk) {
      if (hasNext) {
        if (kk == 0) { ST_A(0, kbn, nb); ST_A(2, kbn, nb); ST_B(0, kbn, nb); ST_B(1, kbn, nb); }
        else         { ST_B(2, kbn, nb); ST_B(3, kbn, nb); ST_A(1, kbn, nb); ST_A(3, kbn, nb); }
      }
      bf16x8 af[8], bfr[4];
#pragma unroll
      for (int mf = 0; mf < 8; ++mf)
        af[mf] = *(const bf16x8*)(cb + (wm * 128 + mf * 16 + l15) * 128 + coff[kk]);
#pragma unroll
      for (int nf = 0; nf < 4; ++nf)
        bfr[nf] = *(const bf16x8*)(cb + ASZ + (wn * 64 + nf * 16 + l15) * 128 + coff[kk]);
      __builtin_amdgcn_s_setprio(1);
#pragma unroll
      for (int mf = 0; mf < 8; ++mf)
#pragma unroll
        for (int nf = 0; nf < 4; ++nf)
          acc[mf][nf] = __builtin_amdgcn_mfma_f32_16x16x32_bf16(
              af[mf], bfr[nf], acc[mf][nf], 0, 0, 0);
      __builtin_amdgcn_s_setprio(0);
    }
    asm volatile("s_waitcnt vmcnt(0)" ::: "memory");
    __builtin_amdgcn_s_barrier();
  }
#undef ST_A
#undef ST_B

#pragma unroll
  for (int mf = 0; mf < 8; ++mf) {
#pragma unroll
    for (int nf = 0; nf < 4; ++nf) {
      const int col = n0 + wn * 64 + nf * 16 + l15;
      const float bb = bias0[col];
#pragma unroll
      for (int r = 0; r < 4; ++r) {
        const int row = m0 + wm * 128 + mf * 16 + l4 * 4 + r;
        float y = acc[mf][nf][r] + bb;
        if constexpr (MODE == 1) y = fmaxf(y, 0.f);
        ((bf16*)out)[(size_t)row * N + col] = __float2bfloat16(y);
      }
    }
  }
}

// ---------------------------------------------------------------------------
// gemmB: BM=128,BN=256,BK=64, 512 thr, 8 waves (2M x 4N). (frozen)
// MODE 0: QKV permute+split; MODE 2: f32 out += res
// ---------------------------------------------------------------------------
template <int MODE>
__global__ __launch_bounds__(512, 2) void gemmB(
    const bf16* __restrict__ A, const bf16* __restrict__ Bw,
    const float* __restrict__ bias0, const float* __restrict__ bias1,
    const float* __restrict__ bias2, const float* __restrict__ res,
    void* __restrict__ out, int M, int N, int K) {
  constexpr int ASZ = 128 * 128;
  constexpr int TILE = ASZ + 256 * 128;  // 48 KB
  __shared__ __align__(16) char smem[3 * TILE];  // 144 KB

  const int t = threadIdx.x;
  const int l = t & 63, l15 = l & 15, l4 = (l >> 4) & 3;
  const int w = t >> 6, wm = w >> 2, wn = w & 3;
  const int gx = gridDim.x;
  const int nwg = gx * gridDim.y;
  const int bid0 = blockIdx.y * gx + blockIdx.x;
  const int bid = (bid0 & 7) * (nwg >> 3) + (bid0 >> 3);
  const int m0 = (bid / gx) * 128, n0 = (bid % gx) * 256;

  const int sr = t >> 3;
  const int scol = 8 * ((t & 7) ^ (sr & 7));
  const int swz = (l15 & 7) << 4;
  int coff[2];
  coff[0] = (l4 * 16) ^ swz;
  coff[1] = (64 + l4 * 16) ^ swz;

#define ST_A(j, kb, buf)                                          \
  gload16(&A[(size_t)(m0 + (j) * 64 + sr) * K + (kb) + scol],     \
          (void*)(smem + (buf) * TILE + (j) * 8192 + t * 16))
#define ST_B(j, kb, buf)                                          \
  gload16(&Bw[(size_t)(n0 + (j) * 64 + sr) * K + (kb) + scol],    \
          (void*)(smem + (buf) * TILE + ASZ + (j) * 8192 + t * 16))

  f32x4 acc[4][4] = {};
  const int NTm = K >> 6;

  ST_B(0, 0, 0); ST_B(1, 0, 0); ST_B(2, 0, 0);
  ST_B(3, 0, 0); ST_A(0, 0, 0); ST_A(1, 0, 0);
  ST_B(0, 64, 1); ST_B(1, 64, 1); ST_B(2, 64, 1);
  ST_B(3, 64, 1); ST_A(0, 64, 1); ST_A(1, 64, 1);
  asm volatile("s_waitcnt vmcnt(6)" ::: "memory");
  __builtin_amdgcn_s_barrier();

  for (int kt = 0; kt < NTm; ++kt) {
    const char* cb = smem + (kt % 3) * TILE;
    const int nb = (kt + 2) % 3;
    const int kbn = (kt + 2) << 6;
    const bool iss = (kt + 2 < NTm);
    if (iss) {
      ST_B(0, kbn, nb); ST_B(1, kbn, nb); ST_B(2, kbn, nb);
      ST_B(3, kbn, nb); ST_A(0, kbn, nb); ST_A(1, kbn, nb);
    }
    bf16x8 af[2][4], bfr[2][4];
#pragma unroll
    for (int kk = 0; kk < 2; ++kk) {
#pragma unroll
      for (int mf = 0; mf < 4; ++mf)
        af[kk][mf] = *(const bf16x8*)(cb + (wm * 64 + mf * 16 + l15) * 128 + coff[kk]);
#pragma unroll
      for (int nf = 0; nf < 4; ++nf)
        bfr[kk][nf] = *(const bf16x8*)(cb + ASZ + (wn * 64 + nf * 16 + l15) * 128 + coff[kk]);
    }
    __builtin_amdgcn_s_setprio(1);
#pragma unroll
    for (int kk = 0; kk < 2; ++kk)
#pragma unroll
      for (int mf = 0; mf < 4; ++mf)
#pragma unroll
        for (int nf = 0; nf < 4; ++nf)
          acc[mf][nf] = __builtin_amdgcn_mfma_f32_16x16x32_bf16(
              af[kk][mf], bfr[kk][nf], acc[mf][nf], 0, 0, 0);
    __builtin_amdgcn_s_setprio(0);
    if (iss) asm volatile("s_waitcnt vmcnt(6)" ::: "memory");
    else     asm volatile("s_waitcnt vmcnt(0)" ::: "memory");
    __builtin_amdgcn_s_barrier();
  }
#undef ST_A
#undef ST_B

#pragma unroll
  for (int mf = 0; mf < 4; ++mf) {
#pragma unroll
    for (int nf = 0; nf < 4; ++nf) {
      const int col = n0 + wn * 64 + nf * 16 + l15;
      float bb;
      if constexpr (MODE == 0) {
        const int sel = col >> 10;
        const float* bp = (sel == 0) ? bias0 : ((sel == 1) ? bias1 : bias2);
        bb = bp[col & 1023];
      } else {
        bb = bias0[col];
      }
#pragma unroll
      for (int r = 0; r < 4; ++r) {
        const int row = m0 + wm * 64 + mf * 16 + l4 * 4 + r;
        float y = acc[mf][nf][r] + bb;
        if constexpr (MODE == 0) {
          const int sel = col >> 10;
          const int c10 = col & 1023;
          const size_t dst = (size_t)sel * (NTOK * 1024) +
                             (size_t)((row >> 11) * NHEAD + (c10 >> 6)) * (SEQ * HEAD_DIM) +
                             (size_t)(row & (SEQ - 1)) * HEAD_DIM + (c10 & 63);
          ((bf16*)out)[dst] = __float2bfloat16(y);
        } else {
          y += res[(size_t)row * N + col];
          ((float*)out)[(size_t)row * N + col] = y;
        }
      }
    }
  }
}

// ---------------------------------------------------------------------------
// Flash attention v11 (r15 best): 512 thr / 8 waves / QBLK=256, (512,4),
// register-fit body (no pw array; kk-outer QK and PV; pb packed inline).
// ---------------------------------------------------------------------------
#define SCL 0.18033688011112042f  // 0.125 * log2(e)
#define NT (SEQ / 64)

__global__ __launch_bounds__(512, 4) void flash_attn(
    const bf16* __restrict__ Q, const bf16* __restrict__ K,
    const bf16* __restrict__ V, bf16* __restrict__ O) {
  __shared__ char smem[32768];  // K dbuf @0..16K, Vt dbuf @16K..32K
  const int t = threadIdx.x;
  const int w = t >> 6, l = t & 63;
  const int l15 = l & 15, l4 = l >> 4;
  const int bid0 = blockIdx.y * 8 + blockIdx.x;
  const int bid = (bid0 & 7) * 64 + (bid0 >> 3);
  const int bx = bid & 7, bh = bid >> 3;
  const size_t base = (size_t)bh * (SEQ * HEAD_DIM);
  const int q0 = bx * 256 + w * 32;

  int krow[4], kswz[4];
#pragma unroll
  for (int ni = 0; ni < 4; ++ni) {
    const int kr = (ni >> 1) * 32 + (ni & 1) * 4 + (l15 >> 2) * 8 + (l15 & 3);
    krow[ni] = kr * 128;
    kswz[ni] = ((kr & 3) | (((kr >> 3) & 1) << 2)) << 4;
  }

  bf16x8 qf[2][2];
#pragma unroll
  for (int mi = 0; mi < 2; ++mi)
#pragma unroll
    for (int kk = 0; kk < 2; ++kk)
      qf[mi][kk] = *(const bf16x8*)&Q[base + (size_t)(q0 + mi * 16 + l15) * 64 + kk * 32 + l4 * 8];

  f32x4 accO[2][4] = {};
  float m_run[2], l_run[2];
#pragma unroll
  for (int mi = 0; mi < 2; ++mi) { m_run[mi] = -1e30f; l_run[mi] = 0.f; }

  short vg[8];

  const int r0 = t >> 3;
  const int c0 = 8 * ((t & 7) ^ ((r0 & 3) | (((r0 >> 3) & 1) << 2)));
  const short* kg = (const short*)K + base + r0 * 64 + c0;
  const int dv = t & 63;
  const int kb8 = (t >> 6) * 8;
  const short* vp = (const short*)V + base + (size_t)kb8 * 64 + dv;
  const int vtbyte = dv * 128 + ((kb8 * 2) ^ ((dv & 7) << 4));

#define STAGE_K(bufofs)                                          \
  {                                                              \
    gload16(kg, (void*)(smem + (bufofs) + w * 1024));            \
    kg += 4096;                                                  \
  }

#define V_GATHER()                                               \
  {                                                              \
    _Pragma("unroll") for (int j_ = 0; j_ < 8; ++j_)             \
        vg[j_] = vp[j_ * 64];                                    \
    vp += 4096;                                                  \
  }

#define VT_WRITE(bufofs)                                         \
  {                                                              \
    bf16x8 vv;                                                   \
    _Pragma("unroll") for (int j_ = 0; j_ < 8; ++j_)             \
        vv[j_] = vg[j_];                                         \
    *(bf16x8*)(smem + (bufofs) + vtbyte) = vv;                   \
  }

  STAGE_K(0);
  V_GATHER();
  VT_WRITE(16384);
  __syncthreads();

  for (int it = 0; it < NT; ++it) {
    const int cur = it & 1;
    const char* Kb = (const char*)smem + cur * 8192;
    const char* Vb = (const char*)smem + 16384 + cur * 8192;
    const bool pre = (it + 1 < NT);
    if (pre) {
      STAGE_K((cur ^ 1) * 8192);
      V_GATHER();
    }

    // ---- QK^T (swapped), kk-outer so kf lives briefly ----
    f32x4 s[2][4] = {};
#pragma unroll
    for (int kk = 0; kk < 2; ++kk) {
      bf16x8 kf[4];
#pragma unroll
      for (int ni = 0; ni < 4; ++ni)
        kf[ni] = *(const bf16x8*)(Kb + krow[ni] + ((kk * 64 + l4 * 16) ^ kswz[ni]));
      __builtin_amdgcn_s_setprio(1);
#pragma unroll
      for (int mi = 0; mi < 2; ++mi)
#pragma unroll
        for (int ni = 0; ni < 4; ++ni)
          s[mi][ni] = __builtin_amdgcn_mfma_f32_16x16x32_bf16(kf[ni], qf[mi][kk], s[mi][ni], 0, 0, 0);
      __builtin_amdgcn_s_setprio(0);
    }

    // ---- softmax per mi (in place on s) ----
#pragma unroll
    for (int mi = 0; mi < 2; ++mi) {
      const float t0 = max3f(s[mi][0][0], s[mi][0][1], s[mi][0][2]);
      const float t1 = max3f(s[mi][0][3], s[mi][1][0], s[mi][1][1]);
      const float t2 = max3f(s[mi][1][2], s[mi][1][3], s[mi][2][0]);
      const float t3 = max3f(s[mi][2][1], s[mi][2][2], s[mi][2][3]);
      const float t4 = max3f(s[mi][3][0], s[mi][3][1], s[mi][3][2]);
      float mx = fmaxf(max3f(t1, t2, t3), fmaxf(t4, fmaxf(t0, s[mi][3][3])));
      mx = fmaxf(mx, __shfl_xor(mx, 16));
      mx = fmaxf(mx, __shfl_xor(mx, 32));
      const float mxs = mx * SCL;
      // defer-rescale (T13)
      if (__any(mxs > m_run[mi] + 8.f)) {
        const float mn = fmaxf(m_run[mi], mxs);
        const float c = fexp2(m_run[mi] - mn);
        m_run[mi] = mn;
        l_run[mi] *= c;
#pragma unroll
        for (int ni = 0; ni < 4; ++ni)
#pragma unroll
          for (int r = 0; r < 4; ++r) accO[mi][ni][r] *= c;
      }
      float rs = 0.f;
#pragma unroll
      for (int ni = 0; ni < 4; ++ni)
#pragma unroll
        for (int r = 0; r < 4; ++r) {
          const float p = fexp2(fmaf(s[mi][ni][r], SCL, -m_run[mi]));
          s[mi][ni][r] = p;
          rs += p;
        }
      rs += __shfl_xor(rs, 16);
      rs += __shfl_xor(rs, 32);
      l_run[mi] += rs;
    }

    // ---- PV: kk-outer, pb packed inline from live s ----
#pragma unroll
    for (int kk = 0; kk < 2; ++kk) {
      bf16x8 vf[4];
#pragma unroll
      for (int ni = 0; ni < 4; ++ni)
        vf[ni] = *(const bf16x8*)(Vb + (ni * 16 + l15) * 128 +
                                  ((kk * 64 + l4 * 16) ^ ((l15 & 7) << 4)));
#pragma unroll
      for (int mi = 0; mi < 2; ++mi) {
        union { unsigned u[4]; bf16x8 h; } pb;
#pragma unroll
        for (int jj = 0; jj < 4; ++jj) {
          const int ni = 2 * kk + (jj >> 1);
          pb.u[jj] = pkbf16(s[mi][ni][2 * (jj & 1)], s[mi][ni][2 * (jj & 1) + 1]);
        }
        __builtin_amdgcn_s_setprio(1);
#pragma unroll
        for (int ni = 0; ni < 4; ++ni)
          accO[mi][ni] = __builtin_amdgcn_mfma_f32_16x16x32_bf16(vf[ni], pb.h, accO[mi][ni], 0, 0, 0);
        __builtin_amdgcn_s_setprio(0);
      }
    }

    if (pre) VT_WRITE(16384 + (cur ^ 1) * 8192);
    __syncthreads();
  }

  // ---- epilogue: bounce O^T through LDS (4 KB/wave) for coalesced stores ----
  char* ob = smem + w * 4096;
#pragma unroll
  for (int mi = 0; mi < 2; ++mi) {
    const float inv = 1.f / l_run[mi];
    const int qr = mi * 16 + l15;
    const int sw = (qr & 7) << 4;
#pragma unroll
    for (int ni = 0; ni < 4; ++ni)
#pragma unroll
      for (int rr = 0; rr < 2; ++rr) {
        const unsigned pk = pkbf16(accO[mi][ni][2 * rr] * inv, accO[mi][ni][2 * rr + 1] * inv);
        *(unsigned*)(ob + qr * 128 + ((ni * 32 + l4 * 8 + 4 * rr) ^ sw)) = pk;
      }
  }
  asm volatile("s_waitcnt lgkmcnt(0)" ::: "memory");
  __builtin_amdgcn_sched_barrier(0);

  const int b = bh >> 4, h = bh & 15;
  const int hr = l >> 1, hf = l & 1;
  const size_t orow = ((size_t)b * SEQ + bx * 256 + w * 32 + hr) * D_MODEL + h * HEAD_DIM + hf * 32;
#pragma unroll
  for (int c = 0; c < 4; ++c) {
    bf16x8 vv = *(const bf16x8*)(ob + hr * 128 + (((hf * 64) + c * 16) ^ ((hr & 7) << 4)));
    *(bf16x8*)&O[orow + c * 8] = vv;
  }
}

// ---------------------------------------------------------------------------
extern "C" void kernel_launch(void* const* d_in, const int* in_sizes, int n_in,
                              void* d_out, int out_size, void* d_ws, size_t ws_size,
                              hipStream_t stream) {
  const float* x     = (const float*)d_in[0];
  const float* Wq    = (const float*)d_in[1];
  const float* bq    = (const float*)d_in[2];
  const float* Wk    = (const float*)d_in[3];
  const float* bk    = (const float*)d_in[4];
  const float* Wv    = (const float*)d_in[5];
  const float* bv    = (const float*)d_in[6];
  const float* Wo    = (const float*)d_in[7];
  const float* bo    = (const float*)d_in[8];
  const float* W1    = (const float*)d_in[9];
  const float* b1    = (const float*)d_in[10];
  const float* W2    = (const float*)d_in[11];
  const float* b2    = (const float*)d_in[12];
  const float* ln1_g = (const float*)d_in[13];
  const float* ln1_b = (const float*)d_in[14];
  const float* ln2_g = (const float*)d_in[15];
  const float* ln2_b = (const float*)d_in[16];

  const size_t MB = 1ull << 20;
  char* ws = (char*)d_ws;
  bf16* wqkv = (bf16*)(ws + 0 * MB);    // 6 MB: [Wq;Wk;Wv] rows, K-contig
  bf16* wo_b = (bf16*)(ws + 6 * MB);
  bf16* w1_b = (bf16*)(ws + 8 * MB);    // 8 MB
  bf16* w2_b = (bf16*)(ws + 16 * MB);   // 8 MB
  bf16* xn   = (bf16*)(ws + 24 * MB);   // 16 MB: xn / attn_out / xn2
  bf16* qb   = (bf16*)(ws + 40 * MB);   // 16 MB (q,k,v contiguous)
  bf16* kbuf = (bf16*)(ws + 56 * MB);   // 16 MB
  bf16* vb   = (bf16*)(ws + 72 * MB);   // 16 MB
  bf16* hb   = (bf16*)(ws + 40 * MB);   // 64 MB (reuses q/k/v after attention)
  float* x1  = (float*)(ws + 104 * MB); // 32 MB

  // weight conversion + LN1 fused into one launch
  cvt_ln<<<12288 + NTOK, 256, 0, stream>>>(W1, W2, Wq, Wk, Wv, Wo,
                                           w1_b, w2_b, wqkv, wo_b,
                                           x, ln1_g, ln1_b, xn);

  // QKV fused: [8192,3072] = xn @ wqkv^T -> permuted/split q/k/v
  gemmB<0><<<dim3(3072 / 256, NTOK / 128), 512, 0, stream>>>(
      xn, wqkv, bq, bk, bv, nullptr, qb, NTOK, 3072, 1024);

  flash_attn<<<dim3(SEQ / 256, 4 * NHEAD), 512, 0, stream>>>(qb, kbuf, vb, xn);

  // Wo + residual(x) -> x1 (fp32)
  gemmB<2><<<dim3(1024 / 256, NTOK / 128), 512, 0, stream>>>(
      xn, wo_b, bo, bo, bo, x, x1, NTOK, 1024, 1024);

  layernorm_kernel<<<NTOK, 256, 0, stream>>>(x1, ln2_g, ln2_b, xn);

  // FFN1 (ReLU) -> hb
  gemmA<1><<<dim3(D_FF / 256, NTOK / 256), 512, 0, stream>>>(
      xn, w1_b, b1, hb, NTOK, D_FF, 1024);

  // FFN2 + residual(x1) -> d_out (fp32)
  gemmB<2><<<dim3(1024 / 256, NTOK / 128), 512, 0, stream>>>(
      hb, w2_b, b2, b2, b2, x1, d_out, NTOK, 1024, D_FF);
}

// Round 18
// 367.196 us; speedup vs baseline: 1.8264x; 1.0097x over previous
//
#include <hip/hip_runtime.h>
#include <hip/hip_bf16.h>

using bf16 = __hip_bfloat16;
typedef __attribute__((ext_vector_type(8))) short bf16x8;
typedef __attribute__((ext_vector_type(4))) float f32x4;

#define D_MODEL 1024
#define NHEAD 16
#define HEAD_DIM 64
#define D_FF 4096
#define SEQ 2048
#define NTOK 8192  // 4 * 2048

__device__ __forceinline__ void gload16(const void* g, void* l) {
  __builtin_amdgcn_global_load_lds((const __attribute__((address_space(1))) void*)g,
                                   (__attribute__((address_space(3))) void*)l, 16, 0, 0);
}

__device__ __forceinline__ unsigned pkbf16(float lo, float hi) {
  unsigned r;
  asm("v_cvt_pk_bf16_f32 %0, %1, %2" : "=v"(r) : "v"(lo), "v"(hi));
  return r;
}

// raw v_exp_f32 (2^x): exp2f() lowers to OCML multi-instr; this is 1 VALU op.
__device__ __forceinline__ float fexp2(float x) {
  float r;
  asm("v_exp_f32 %0, %1" : "=v"(r) : "v"(x));
  return r;
}

__device__ __forceinline__ float max3f(float a, float b, float c) {
  return fmaxf(fmaxf(a, b), c);  // fuses to v_max3_f32
}

// ---------------------------------------------------------------------------
// Fused: f32->bf16 weight conversion (blocks 0..12287) + LN1 (blocks 12288+).
// ---------------------------------------------------------------------------
__global__ __launch_bounds__(256) void cvt_ln(
    const float* __restrict__ W1, const float* __restrict__ W2,
    const float* __restrict__ Wq, const float* __restrict__ Wk,
    const float* __restrict__ Wv, const float* __restrict__ Wo,
    bf16* __restrict__ w1_b, bf16* __restrict__ w2_b,
    bf16* __restrict__ wqkv, bf16* __restrict__ wo_b,
    const float* __restrict__ x, const float* __restrict__ g,
    const float* __restrict__ bta, bf16* __restrict__ xn) {
  const int bid = blockIdx.x;
  if (bid < 12288) {
    const float* src;
    bf16* dst;
    int lb;
    if (bid < 4096) { src = W1; dst = w1_b; lb = bid; }
    else if (bid < 8192) { src = W2; dst = w2_b; lb = bid - 4096; }
    else {
      const int j = (bid - 8192) >> 10;
      lb = (bid - 8192) & 1023;
      if (j == 0) { src = Wq; dst = wqkv; }
      else if (j == 1) { src = Wk; dst = wqkv + 1048576; }
      else if (j == 2) { src = Wv; dst = wqkv + 2097152; }
      else { src = Wo; dst = wo_b; }
    }
    const int i = (lb * 256 + threadIdx.x) * 4;
    const float4 v = *(const float4*)&src[i];
    dst[i + 0] = __float2bfloat16(v.x);
    dst[i + 1] = __float2bfloat16(v.y);
    dst[i + 2] = __float2bfloat16(v.z);
    dst[i + 3] = __float2bfloat16(v.w);
    return;
  }
  const int row = bid - 12288, t = threadIdx.x;
  const float4 v = *(const float4*)&x[(size_t)row * D_MODEL + t * 4];
  float s = v.x + v.y + v.z + v.w;
#pragma unroll
  for (int m = 1; m < 64; m <<= 1) s += __shfl_xor(s, m);
  __shared__ float red[4], red2[4];
  const int w = t >> 6, l = t & 63;
  if (l == 0) red[w] = s;
  __syncthreads();
  const float mu = (red[0] + red[1] + red[2] + red[3]) * (1.f / 1024.f);
  const float d0 = v.x - mu, d1 = v.y - mu, d2 = v.z - mu, d3 = v.w - mu;
  float q = d0 * d0 + d1 * d1 + d2 * d2 + d3 * d3;
#pragma unroll
  for (int m = 1; m < 64; m <<= 1) q += __shfl_xor(q, m);
  if (l == 0) red2[w] = q;
  __syncthreads();
  const float var = (red2[0] + red2[1] + red2[2] + red2[3]) * (1.f / 1024.f);
  const float rs = rsqrtf(var + 1e-5f);
  const float4 gg = *(const float4*)&g[t * 4];
  const float4 bb = *(const float4*)&bta[t * 4];
  bf16* o = xn + (size_t)row * D_MODEL + t * 4;
  o[0] = __float2bfloat16(d0 * rs * gg.x + bb.x);
  o[1] = __float2bfloat16(d1 * rs * gg.y + bb.y);
  o[2] = __float2bfloat16(d2 * rs * gg.z + bb.z);
  o[3] = __float2bfloat16(d3 * rs * gg.w + bb.w);
}

// ---------------------------------------------------------------------------
// LayerNorm over D=1024, fp32 in -> bf16 out. One block (256 thr) per row.
// ---------------------------------------------------------------------------
__global__ __launch_bounds__(256) void layernorm_kernel(
    const float* __restrict__ xin, const float* __restrict__ g,
    const float* __restrict__ bta, bf16* __restrict__ out) {
  const int row = blockIdx.x, t = threadIdx.x;
  const float4 v = *(const float4*)&xin[(size_t)row * D_MODEL + t * 4];
  float s = v.x + v.y + v.z + v.w;
#pragma unroll
  for (int m = 1; m < 64; m <<= 1) s += __shfl_xor(s, m);
  __shared__ float red[4], red2[4];
  const int w = t >> 6, l = t & 63;
  if (l == 0) red[w] = s;
  __syncthreads();
  const float mu = (red[0] + red[1] + red[2] + red[3]) * (1.f / 1024.f);
  const float d0 = v.x - mu, d1 = v.y - mu, d2 = v.z - mu, d3 = v.w - mu;
  float q = d0 * d0 + d1 * d1 + d2 * d2 + d3 * d3;
#pragma unroll
  for (int m = 1; m < 64; m <<= 1) q += __shfl_xor(q, m);
  if (l == 0) red2[w] = q;
  __syncthreads();
  const float var = (red2[0] + red2[1] + red2[2] + red2[3]) * (1.f / 1024.f);
  const float rs = rsqrtf(var + 1e-5f);
  const float4 gg = *(const float4*)&g[t * 4];
  const float4 bb = *(const float4*)&bta[t * 4];
  bf16* o = out + (size_t)row * D_MODEL + t * 4;
  o[0] = __float2bfloat16(d0 * rs * gg.x + bb.x);
  o[1] = __float2bfloat16(d1 * rs * gg.y + bb.y);
  o[2] = __float2bfloat16(d2 * rs * gg.z + bb.z);
  o[3] = __float2bfloat16(d3 * rs * gg.w + bb.w);
}

// ---------------------------------------------------------------------------
// gemmA: BM=256,BN=256,BK=64, 512 thr, 8 waves (2M x 4N). (frozen)
// ---------------------------------------------------------------------------
template <int MODE>
__global__ __launch_bounds__(512, 2) void gemmA(
    const bf16* __restrict__ A, const bf16* __restrict__ Bw,
    const float* __restrict__ bias0,
    void* __restrict__ out, int M, int N, int K) {
  constexpr int ASZ = 256 * 128;
  constexpr int TILE = ASZ + 256 * 128;  // 64 KB
  __shared__ __align__(16) char smem[2 * TILE];

  const int t = threadIdx.x;
  const int l = t & 63, l15 = l & 15, l4 = (l >> 4) & 3;
  const int w = t >> 6, wm = w >> 2, wn = w & 3;
  const int gx = gridDim.x;
  const int nwg = gx * gridDim.y;
  const int bid0 = blockIdx.y * gx + blockIdx.x;
  const int bid = (bid0 & 7) * (nwg >> 3) + (bid0 >> 3);
  const int m0 = (bid / gx) * 256, n0 = (bid % gx) * 256;

  const int sr = t >> 3;
  const int scol = 8 * ((t & 7) ^ (sr & 7));
  const int swz = (l15 & 7) << 4;
  int coff[2];
  coff[0] = (l4 * 16) ^ swz;
  coff[1] = (64 + l4 * 16) ^ swz;

#define ST_A(j, kb, buf)                                          \
  gload16(&A[(size_t)(m0 + (j) * 64 + sr) * K + (kb) + scol],     \
          (void*)(smem + (buf) * TILE + (j) * 8192 + t * 16))
#define ST_B(j, kb, buf)                                          \
  gload16(&Bw[(size_t)(n0 + (j) * 64 + sr) * K + (kb) + scol],    \
          (void*)(smem + (buf) * TILE + ASZ + (j) * 8192 + t * 16))

  f32x4 acc[8][4] = {};
  const int NTm = K >> 6;

  ST_A(0, 0, 0); ST_A(2, 0, 0); ST_B(0, 0, 0); ST_B(1, 0, 0);
  ST_B(2, 0, 0); ST_B(3, 0, 0); ST_A(1, 0, 0); ST_A(3, 0, 0);
  asm volatile("s_waitcnt vmcnt(0)" ::: "memory");
  __builtin_amdgcn_s_barrier();

  for (int kt = 0; kt < NTm; ++kt) {
    const char* cb = smem + (kt & 1) * TILE;
    const int nb = (kt & 1) ^ 1;
    const int kbn = (kt + 1) << 6;
    const bool hasNext = (kt + 1 < NTm);
#pragma unroll
    for (int kk = 0; kk < 2; ++kk) {
      if (hasNext) {
        if (kk == 0) { ST_A(0, kbn, nb); ST_A(2, kbn, nb); ST_B(0, kbn, nb); ST_B(1, kbn, nb); }
        else         { ST_B(2, kbn, nb); ST_B(3, kbn, nb); ST_A(1, kbn, nb); ST_A(3, kbn, nb); }
      }
      bf16x8 af[8], bfr[4];
#pragma unroll
      for (int mf = 0; mf < 8; ++mf)
        af[mf] = *(const bf16x8*)(cb + (wm * 128 + mf * 16 + l15) * 128 + coff[kk]);
#pragma unroll
      for (int nf = 0; nf < 4; ++nf)
        bfr[nf] = *(const bf16x8*)(cb + ASZ + (wn * 64 + nf * 16 + l15) * 128 + coff[kk]);
      __builtin_amdgcn_s_setprio(1);
#pragma unroll
      for (int mf = 0; mf < 8; ++mf)
#pragma unroll
        for (int nf = 0; nf < 4; ++nf)
          acc[mf][nf] = __builtin_amdgcn_mfma_f32_16x16x32_bf16(
              af[mf], bfr[nf], acc[mf][nf], 0, 0, 0);
      __builtin_amdgcn_s_setprio(0);
    }
    asm volatile("s_waitcnt vmcnt(0)" ::: "memory");
    __builtin_amdgcn_s_barrier();
  }
#undef ST_A
#undef ST_B

#pragma unroll
  for (int mf = 0; mf < 8; ++mf) {
#pragma unroll
    for (int nf = 0; nf < 4; ++nf) {
      const int col = n0 + wn * 64 + nf * 16 + l15;
      const float bb = bias0[col];
#pragma unroll
      for (int r = 0; r < 4; ++r) {
        const int row = m0 + wm * 128 + mf * 16 + l4 * 4 + r;
        float y = acc[mf][nf][r] + bb;
        if constexpr (MODE == 1) y = fmaxf(y, 0.f);
        ((bf16*)out)[(size_t)row * N + col] = __float2bfloat16(y);
      }
    }
  }
}

// ---------------------------------------------------------------------------
// gemmB: BM=128,BN=256,BK=64, 512 thr, 8 waves (2M x 4N). (frozen)
// MODE 0: QKV permute+split; MODE 2: f32 out += res
// ---------------------------------------------------------------------------
template <int MODE>
__global__ __launch_bounds__(512, 2) void gemmB(
    const bf16* __restrict__ A, const bf16* __restrict__ Bw,
    const float* __restrict__ bias0, const float* __restrict__ bias1,
    const float* __restrict__ bias2, const float* __restrict__ res,
    void* __restrict__ out, int M, int N, int K) {
  constexpr int ASZ = 128 * 128;
  constexpr int TILE = ASZ + 256 * 128;  // 48 KB
  __shared__ __align__(16) char smem[3 * TILE];  // 144 KB

  const int t = threadIdx.x;
  const int l = t & 63, l15 = l & 15, l4 = (l >> 4) & 3;
  const int w = t >> 6, wm = w >> 2, wn = w & 3;
  const int gx = gridDim.x;
  const int nwg = gx * gridDim.y;
  const int bid0 = blockIdx.y * gx + blockIdx.x;
  const int bid = (bid0 & 7) * (nwg >> 3) + (bid0 >> 3);
  const int m0 = (bid / gx) * 128, n0 = (bid % gx) * 256;

  const int sr = t >> 3;
  const int scol = 8 * ((t & 7) ^ (sr & 7));
  const int swz = (l15 & 7) << 4;
  int coff[2];
  coff[0] = (l4 * 16) ^ swz;
  coff[1] = (64 + l4 * 16) ^ swz;

#define ST_A(j, kb, buf)                                          \
  gload16(&A[(size_t)(m0 + (j) * 64 + sr) * K + (kb) + scol],     \
          (void*)(smem + (buf) * TILE + (j) * 8192 + t * 16))
#define ST_B(j, kb, buf)                                          \
  gload16(&Bw[(size_t)(n0 + (j) * 64 + sr) * K + (kb) + scol],    \
          (void*)(smem + (buf) * TILE + ASZ + (j) * 8192 + t * 16))

  f32x4 acc[4][4] = {};
  const int NTm = K >> 6;

  ST_B(0, 0, 0); ST_B(1, 0, 0); ST_B(2, 0, 0);
  ST_B(3, 0, 0); ST_A(0, 0, 0); ST_A(1, 0, 0);
  ST_B(0, 64, 1); ST_B(1, 64, 1); ST_B(2, 64, 1);
  ST_B(3, 64, 1); ST_A(0, 64, 1); ST_A(1, 64, 1);
  asm volatile("s_waitcnt vmcnt(6)" ::: "memory");
  __builtin_amdgcn_s_barrier();

  for (int kt = 0; kt < NTm; ++kt) {
    const char* cb = smem + (kt % 3) * TILE;
    const int nb = (kt + 2) % 3;
    const int kbn = (kt + 2) << 6;
    const bool iss = (kt + 2 < NTm);
    if (iss) {
      ST_B(0, kbn, nb); ST_B(1, kbn, nb); ST_B(2, kbn, nb);
      ST_B(3, kbn, nb); ST_A(0, kbn, nb); ST_A(1, kbn, nb);
    }
    bf16x8 af[2][4], bfr[2][4];
#pragma unroll
    for (int kk = 0; kk < 2; ++kk) {
#pragma unroll
      for (int mf = 0; mf < 4; ++mf)
        af[kk][mf] = *(const bf16x8*)(cb + (wm * 64 + mf * 16 + l15) * 128 + coff[kk]);
#pragma unroll
      for (int nf = 0; nf < 4; ++nf)
        bfr[kk][nf] = *(const bf16x8*)(cb + ASZ + (wn * 64 + nf * 16 + l15) * 128 + coff[kk]);
    }
    __builtin_amdgcn_s_setprio(1);
#pragma unroll
    for (int kk = 0; kk < 2; ++kk)
#pragma unroll
      for (int mf = 0; mf < 4; ++mf)
#pragma unroll
        for (int nf = 0; nf < 4; ++nf)
          acc[mf][nf] = __builtin_amdgcn_mfma_f32_16x16x32_bf16(
              af[kk][mf], bfr[kk][nf], acc[mf][nf], 0, 0, 0);
    __builtin_amdgcn_s_setprio(0);
    if (iss) asm volatile("s_waitcnt vmcnt(6)" ::: "memory");
    else     asm volatile("s_waitcnt vmcnt(0)" ::: "memory");
    __builtin_amdgcn_s_barrier();
  }
#undef ST_A
#undef ST_B

#pragma unroll
  for (int mf = 0; mf < 4; ++mf) {
#pragma unroll
    for (int nf = 0; nf < 4; ++nf) {
      const int col = n0 + wn * 64 + nf * 16 + l15;
      float bb;
      if constexpr (MODE == 0) {
        const int sel = col >> 10;
        const float* bp = (sel == 0) ? bias0 : ((sel == 1) ? bias1 : bias2);
        bb = bp[col & 1023];
      } else {
        bb = bias0[col];
      }
#pragma unroll
      for (int r = 0; r < 4; ++r) {
        const int row = m0 + wm * 64 + mf * 16 + l4 * 4 + r;
        float y = acc[mf][nf][r] + bb;
        if constexpr (MODE == 0) {
          const int sel = col >> 10;
          const int c10 = col & 1023;
          const size_t dst = (size_t)sel * (NTOK * 1024) +
                             (size_t)((row >> 11) * NHEAD + (c10 >> 6)) * (SEQ * HEAD_DIM) +
                             (size_t)(row & (SEQ - 1)) * HEAD_DIM + (c10 & 63);
          ((bf16*)out)[dst] = __float2bfloat16(y);
        } else {
          y += res[(size_t)row * N + col];
          ((float*)out)[(size_t)row * N + col] = y;
        }
      }
    }
  }
}

// ---------------------------------------------------------------------------
// Flash attention v13: r15 body + rowsum moved back to the matrix pipe
// (MFMA-with-ones into a PERSISTENT running zz accumulator, rescaled with
// accO on defer-rescale, read once in epilogue). Removes 32 VALU adds +
// 4 shuffles per iter from the busiest pipe (VALU 57% vs MFMA 29%).
// Register cost ~+12 (ones 4, zz 8, -l_run 2): ~106 of 128 at (512,4).
// ---------------------------------------------------------------------------
#define SCL 0.18033688011112042f  // 0.125 * log2(e)
#define NT (SEQ / 64)

__global__ __launch_bounds__(512, 4) void flash_attn(
    const bf16* __restrict__ Q, const bf16* __restrict__ K,
    const bf16* __restrict__ V, bf16* __restrict__ O) {
  __shared__ char smem[32768];  // K dbuf @0..16K, Vt dbuf @16K..32K
  const int t = threadIdx.x;
  const int w = t >> 6, l = t & 63;
  const int l15 = l & 15, l4 = l >> 4;
  const int bid0 = blockIdx.y * 8 + blockIdx.x;
  const int bid = (bid0 & 7) * 64 + (bid0 >> 3);
  const int bx = bid & 7, bh = bid >> 3;
  const size_t base = (size_t)bh * (SEQ * HEAD_DIM);
  const int q0 = bx * 256 + w * 32;

  int krow[4], kswz[4];
#pragma unroll
  for (int ni = 0; ni < 4; ++ni) {
    const int kr = (ni >> 1) * 32 + (ni & 1) * 4 + (l15 >> 2) * 8 + (l15 & 3);
    krow[ni] = kr * 128;
    kswz[ni] = ((kr & 3) | (((kr >> 3) & 1) << 2)) << 4;
  }

  bf16x8 qf[2][2];
#pragma unroll
  for (int mi = 0; mi < 2; ++mi)
#pragma unroll
    for (int kk = 0; kk < 2; ++kk)
      qf[mi][kk] = *(const bf16x8*)&Q[base + (size_t)(q0 + mi * 16 + l15) * 64 + kk * 32 + l4 * 8];

  bf16x8 ones;
#pragma unroll
  for (int j = 0; j < 8; ++j) ones[j] = (short)0x3F80;  // bf16 1.0

  f32x4 accO[2][4] = {};
  f32x4 zz[2] = {};  // running rowsum accumulator (matrix pipe)
  float m_run[2];
#pragma unroll
  for (int mi = 0; mi < 2; ++mi) m_run[mi] = -1e30f;

  short vg[8];

  const int r0 = t >> 3;
  const int c0 = 8 * ((t & 7) ^ ((r0 & 3) | (((r0 >> 3) & 1) << 2)));
  const short* kg = (const short*)K + base + r0 * 64 + c0;
  const int dv = t & 63;
  const int kb8 = (t >> 6) * 8;
  const short* vp = (const short*)V + base + (size_t)kb8 * 64 + dv;
  const int vtbyte = dv * 128 + ((kb8 * 2) ^ ((dv & 7) << 4));

#define STAGE_K(bufofs)                                          \
  {                                                              \
    gload16(kg, (void*)(smem + (bufofs) + w * 1024));            \
    kg += 4096;                                                  \
  }

#define V_GATHER()                                               \
  {                                                              \
    _Pragma("unroll") for (int j_ = 0; j_ < 8; ++j_)             \
        vg[j_] = vp[j_ * 64];                                    \
    vp += 4096;                                                  \
  }

#define VT_WRITE(bufofs)                                         \
  {                                                              \
    bf16x8 vv;                                                   \
    _Pragma("unroll") for (int j_ = 0; j_ < 8; ++j_)             \
        vv[j_] = vg[j_];                                         \
    *(bf16x8*)(smem + (bufofs) + vtbyte) = vv;                   \
  }

  STAGE_K(0);
  V_GATHER();
  VT_WRITE(16384);
  __syncthreads();

  for (int it = 0; it < NT; ++it) {
    const int cur = it & 1;
    const char* Kb = (const char*)smem + cur * 8192;
    const char* Vb = (const char*)smem + 16384 + cur * 8192;
    const bool pre = (it + 1 < NT);
    if (pre) {
      STAGE_K((cur ^ 1) * 8192);
      V_GATHER();
    }

    // ---- QK^T (swapped), kk-outer so kf lives briefly ----
    f32x4 s[2][4] = {};
#pragma unroll
    for (int kk = 0; kk < 2; ++kk) {
      bf16x8 kf[4];
#pragma unroll
      for (int ni = 0; ni < 4; ++ni)
        kf[ni] = *(const bf16x8*)(Kb + krow[ni] + ((kk * 64 + l4 * 16) ^ kswz[ni]));
      __builtin_amdgcn_s_setprio(1);
#pragma unroll
      for (int mi = 0; mi < 2; ++mi)
#pragma unroll
        for (int ni = 0; ni < 4; ++ni)
          s[mi][ni] = __builtin_amdgcn_mfma_f32_16x16x32_bf16(kf[ni], qf[mi][kk], s[mi][ni], 0, 0, 0);
      __builtin_amdgcn_s_setprio(0);
    }

    // ---- softmax per mi (in place on s; rowsum deferred to matrix pipe) ----
#pragma unroll
    for (int mi = 0; mi < 2; ++mi) {
      const float t0 = max3f(s[mi][0][0], s[mi][0][1], s[mi][0][2]);
      const float t1 = max3f(s[mi][0][3], s[mi][1][0], s[mi][1][1]);
      const float t2 = max3f(s[mi][1][2], s[mi][1][3], s[mi][2][0]);
      const float t3 = max3f(s[mi][2][1], s[mi][2][2], s[mi][2][3]);
      const float t4 = max3f(s[mi][3][0], s[mi][3][1], s[mi][3][2]);
      float mx = fmaxf(max3f(t1, t2, t3), fmaxf(t4, fmaxf(t0, s[mi][3][3])));
      mx = fmaxf(mx, __shfl_xor(mx, 16));
      mx = fmaxf(mx, __shfl_xor(mx, 32));
      const float mxs = mx * SCL;
      // defer-rescale (T13): rescale accO AND zz together (same basis)
      if (__any(mxs > m_run[mi] + 8.f)) {
        const float mn = fmaxf(m_run[mi], mxs);
        const float c = fexp2(m_run[mi] - mn);
        m_run[mi] = mn;
#pragma unroll
        for (int ni = 0; ni < 4; ++ni)
#pragma unroll
          for (int r = 0; r < 4; ++r) accO[mi][ni][r] *= c;
#pragma unroll
        for (int r = 0; r < 4; ++r) zz[mi][r] *= c;
      }
#pragma unroll
      for (int ni = 0; ni < 4; ++ni)
#pragma unroll
        for (int r = 0; r < 4; ++r)
          s[mi][ni][r] = fexp2(fmaf(s[mi][ni][r], SCL, -m_run[mi]));
    }

    // ---- PV: kk-outer, pb packed inline; rowsum rides MFMA-with-ones ----
#pragma unroll
    for (int kk = 0; kk < 2; ++kk) {
      bf16x8 vf[4];
#pragma unroll
      for (int ni = 0; ni < 4; ++ni)
        vf[ni] = *(const bf16x8*)(Vb + (ni * 16 + l15) * 128 +
                                  ((kk * 64 + l4 * 16) ^ ((l15 & 7) << 4)));
#pragma unroll
      for (int mi = 0; mi < 2; ++mi) {
        union { unsigned u[4]; bf16x8 h; } pb;
#pragma unroll
        for (int jj = 0; jj < 4; ++jj) {
          const int ni = 2 * kk + (jj >> 1);
          pb.u[jj] = pkbf16(s[mi][ni][2 * (jj & 1)], s[mi][ni][2 * (jj & 1) + 1]);
        }
        __builtin_amdgcn_s_setprio(1);
#pragma unroll
        for (int ni = 0; ni < 4; ++ni)
          accO[mi][ni] = __builtin_amdgcn_mfma_f32_16x16x32_bf16(vf[ni], pb.h, accO[mi][ni], 0, 0, 0);
        zz[mi] = __builtin_amdgcn_mfma_f32_16x16x32_bf16(ones, pb.h, zz[mi], 0, 0, 0);
        __builtin_amdgcn_s_setprio(0);
      }
    }

    if (pre) VT_WRITE(16384 + (cur ^ 1) * 8192);
    __syncthreads();
  }

  // ---- epilogue: bounce O^T through LDS (4 KB/wave) for coalesced stores ----
  char* ob = smem + w * 4096;
#pragma unroll
  for (int mi = 0; mi < 2; ++mi) {
    const float inv = 1.f / zz[mi][0];
    const int qr = mi * 16 + l15;
    const int sw = (qr & 7) << 4;
#pragma unroll
    for (int ni = 0; ni < 4; ++ni)
#pragma unroll
      for (int rr = 0; rr < 2; ++rr) {
        const unsigned pk = pkbf16(accO[mi][ni][2 * rr] * inv, accO[mi][ni][2 * rr + 1] * inv);
        *(unsigned*)(ob + qr * 128 + ((ni * 32 + l4 * 8 + 4 * rr) ^ sw)) = pk;
      }
  }
  asm volatile("s_waitcnt lgkmcnt(0)" ::: "memory");
  __builtin_amdgcn_sched_barrier(0);

  const int b = bh >> 4, h = bh & 15;
  const int hr = l >> 1, hf = l & 1;
  const size_t orow = ((size_t)b * SEQ + bx * 256 + w * 32 + hr) * D_MODEL + h * HEAD_DIM + hf * 32;
#pragma unroll
  for (int c = 0; c < 4; ++c) {
    bf16x8 vv = *(const bf16x8*)(ob + hr * 128 + (((hf * 64) + c * 16) ^ ((hr & 7) << 4)));
    *(bf16x8*)&O[orow + c * 8] = vv;
  }
}

// ---------------------------------------------------------------------------
extern "C" void kernel_launch(void* const* d_in, const int* in_sizes, int n_in,
                              void* d_out, int out_size, void* d_ws, size_t ws_size,
                              hipStream_t stream) {
  const float* x     = (const float*)d_in[0];
  const float* Wq    = (const float*)d_in[1];
  const float* bq    = (const float*)d_in[2];
  const float* Wk    = (const float*)d_in[3];
  const float* bk    = (const float*)d_in[4];
  const float* Wv    = (const float*)d_in[5];
  const float* bv    = (const float*)d_in[6];
  const float* Wo    = (const float*)d_in[7];
  const float* bo    = (const float*)d_in[8];
  const float* W1    = (const float*)d_in[9];
  const float* b1    = (const float*)d_in[10];
  const float* W2    = (const float*)d_in[11];
  const float* b2    = (const float*)d_in[12];
  const float* ln1_g = (const float*)d_in[13];
  const float* ln1_b = (const float*)d_in[14];
  const float* ln2_g = (const float*)d_in[15];
  const float* ln2_b = (const float*)d_in[16];

  const size_t MB = 1ull << 20;
  char* ws = (char*)d_ws;
  bf16* wqkv = (bf16*)(ws + 0 * MB);    // 6 MB: [Wq;Wk;Wv] rows, K-contig
  bf16* wo_b = (bf16*)(ws + 6 * MB);
  bf16* w1_b = (bf16*)(ws + 8 * MB);    // 8 MB
  bf16* w2_b = (bf16*)(ws + 16 * MB);   // 8 MB
  bf16* xn   = (bf16*)(ws + 24 * MB);   // 16 MB: xn / attn_out / xn2
  bf16* qb   = (bf16*)(ws + 40 * MB);   // 16 MB (q,k,v contiguous)
  bf16* kbuf = (bf16*)(ws + 56 * MB);   // 16 MB
  bf16* vb   = (bf16*)(ws + 72 * MB);   // 16 MB
  bf16* hb   = (bf16*)(ws + 40 * MB);   // 64 MB (reuses q/k/v after attention)
  float* x1  = (float*)(ws + 104 * MB); // 32 MB

  // weight conversion + LN1 fused into one launch
  cvt_ln<<<12288 + NTOK, 256, 0, stream>>>(W1, W2, Wq, Wk, Wv, Wo,
                                           w1_b, w2_b, wqkv, wo_b,
                                           x, ln1_g, ln1_b, xn);

  // QKV fused: [8192,3072] = xn @ wqkv^T -> permuted/split q/k/v
  gemmB<0><<<dim3(3072 / 256, NTOK / 128), 512, 0, stream>>>(
      xn, wqkv, bq, bk, bv, nullptr, qb, NTOK, 3072, 1024);

  flash_attn<<<dim3(SEQ / 256, 4 * NHEAD), 512, 0, stream>>>(qb, kbuf, vb, xn);

  // Wo + residual(x) -> x1 (fp32)
  gemmB<2><<<dim3(1024 / 256, NTOK / 128), 512, 0, stream>>>(
      xn, wo_b, bo, bo, bo, x, x1, NTOK, 1024, 1024);

  layernorm_kernel<<<NTOK, 256, 0, stream>>>(x1, ln2_g, ln2_b, xn);

  // FFN1 (ReLU) -> hb
  gemmA<1><<<dim3(D_FF / 256, NTOK / 256), 512, 0, stream>>>(
      xn, w1_b, b1, hb, NTOK, D_FF, 1024);

  // FFN2 + residual(x1) -> d_out (fp32)
  gemmB<2><<<dim3(1024 / 256, NTOK / 128), 512, 0, stream>>>(
      hb, w2_b, b2, b2, b2, x1, d_out, NTOK, 1024, D_FF);
}